// Round 3
// baseline (594.735 us; speedup 1.0000x reference)
//
#include <hip/hip_runtime.h>

// ---------- types ----------
typedef __attribute__((ext_vector_type(8))) short bf16x8;
typedef __attribute__((ext_vector_type(4))) float f32x4;

#define N_ROWS 3136
#define M_COLS 20000
#define KDIM   1536
#define BM     256
#define BN     256
#define BK     64
#define NT     24             // KDIM / BK
#define NCT2   79             // ceil(20000/256)
#define NRT2   13             // ceil(3136/256)
#define NWG    (NCT2 * NRT2)  // 1027
#define PPR2   (NCT2 * 9)     // 711

#define GLOAD_LDS16(g, l) __builtin_amdgcn_global_load_lds( \
    (const __attribute__((address_space(1))) unsigned int*)(g), \
    (__attribute__((address_space(3))) unsigned int*)(l), 16, 0, 0)

__device__ inline unsigned short f2bf(float f) {
    unsigned u = __float_as_uint(f);
    u += 0x7FFFu + ((u >> 16) & 1u);   // RNE
    return (unsigned short)(u >> 16);
}

// sorted ascending insert, drop old max; all indices static after unroll
__device__ inline void t9_insert(float (&t)[9], float v) {
    #pragma unroll
    for (int s = 8; s >= 1; --s)
        t[s] = (v <= t[s-1]) ? t[s-1] : fminf(t[s], v);
    t[0] = fminf(t[0], v);
}

// ---------- fused f32->bf16 conversion + row squared norms (wave per row) ----------
__global__ void cvt_norm_kernel(const float* __restrict__ src,
                                unsigned short* __restrict__ dst,
                                float* __restrict__ norms, int rows) {
    int lane = threadIdx.x & 63;
    int row = blockIdx.x * (blockDim.x >> 6) + (threadIdx.x >> 6);
    if (row >= rows) return;
    const float4* p = (const float4*)(src + (size_t)row * KDIM);
    ushort4* q = (ushort4*)(dst + (size_t)row * KDIM);
    float s = 0.f;
    #pragma unroll
    for (int i = 0; i < 6; ++i) {              // 384 float4 / 64 lanes
        float4 v = p[lane + i * 64];
        s += v.x*v.x + v.y*v.y + v.z*v.z + v.w*v.w;
        ushort4 o;
        o.x = f2bf(v.x); o.y = f2bf(v.y); o.z = f2bf(v.z); o.w = f2bf(v.w);
        q[lane + i * 64] = o;
    }
    #pragma unroll
    for (int off = 32; off > 0; off >>= 1) s += __shfl_down(s, off);
    if (lane == 0) norms[row] = s;
}

// ---------- fused distance GEMM + per-tile top-9 : 256x256 8-phase template ----------
// 8 waves (2M x 4N), BK=64, double-buffered 128 KiB LDS, st_16x32 swizzle,
// counted vmcnt(4) at K-tile boundaries, setprio around MFMA clusters.
// LDS layout per buffer (64 KiB): A0[128][64] | A1 | B0 | B1  (16 KiB halves)
// swizzle: byte ^= ((byte>>9)&1)<<5  within each 16 KiB half (involution).

#define STAGE_A(h, s_) do { \
    unsigned dstb = ((unsigned)((s_) & 1) << 16) + ((h) << 14) + ((unsigned)tid << 4); \
    GLOAD_LDS16(gA##h##0 + (size_t)(s_) * BK, smem + dstb); \
    GLOAD_LDS16(gA##h##1 + (size_t)(s_) * BK, smem + dstb + 8192); \
} while (0)
#define STAGE_B(h, s_) do { \
    unsigned dstb = ((unsigned)((s_) & 1) << 16) + 32768u + ((h) << 14) + ((unsigned)tid << 4); \
    GLOAD_LDS16(gB##h##0 + (size_t)(s_) * BK, smem + dstb); \
    GLOAD_LDS16(gB##h##1 + (size_t)(s_) * BK, smem + dstb + 8192); \
} while (0)

#define LDA2(q) \
    a_[0][0] = *(const bf16x8*)(smem + bufR + offA[2*(q)  ][0]); \
    a_[0][1] = *(const bf16x8*)(smem + bufR + offA[2*(q)  ][1]); \
    a_[1][0] = *(const bf16x8*)(smem + bufR + offA[2*(q)+1][0]); \
    a_[1][1] = *(const bf16x8*)(smem + bufR + offA[2*(q)+1][1]);

#define MFMA8(q) \
    _Pragma("unroll") \
    for (int m = 0; m < 2; ++m) { \
        _Pragma("unroll") \
        for (int ni = 0; ni < 4; ++ni) { \
            acc[2*(q)+m][ni] = __builtin_amdgcn_mfma_f32_16x16x32_bf16(a_[m][0], bf[ni][0], acc[2*(q)+m][ni], 0, 0, 0); \
            acc[2*(q)+m][ni] = __builtin_amdgcn_mfma_f32_16x16x32_bf16(a_[m][1], bf[ni][1], acc[2*(q)+m][ni], 0, 0, 0); \
        } \
    }

__global__ __launch_bounds__(512, 2) void dist_topk_kernel(
    const unsigned short* __restrict__ Ag,   // [3136][1536] bf16
    const unsigned short* __restrict__ Bg,   // [20000][1536] bf16
    const float* __restrict__ x2, const float* __restrict__ y2,
    float* __restrict__ partials)
{
    __shared__ __align__(16) unsigned char smem[131072];

    const int tid = threadIdx.x;
    const int wid = tid >> 6, lane = tid & 63;
    const int l15 = lane & 15, l4 = lane >> 4;
    const int wm = wid >> 2, wn = wid & 3;

    // bijective XCD swizzle (m204; 1027 % 8 != 0)
    int orig = blockIdx.x;
    int xcd = orig & 7, li = orig >> 3;
    const int qq = NWG / 8, rr = NWG % 8;   // 128, 3
    int wg = (xcd < rr ? xcd * (qq + 1) : rr * (qq + 1) + (xcd - rr) * qq) + li;
    const int rt = wg / NCT2, ct = wg % NCT2;
    const int rowBase = rt * BM, colBase = ct * BN;

    // ---- staging source pointers: inverse-swizzled global source, linear LDS dest ----
    auto gsrcA = [&](int h, int j) {
        int L = ((j << 9) + tid) << 4;                  // linear dest byte in half
        int s = L ^ (((L >> 9) & 1) << 5);              // involution
        int r = s >> 7, kel = (s & 127) >> 1;
        int grow = rowBase + h * 128 + r; grow = grow < N_ROWS ? grow : N_ROWS - 1;
        return Ag + (size_t)grow * KDIM + kel;
    };
    auto gsrcB = [&](int h, int j) {
        int L = ((j << 9) + tid) << 4;
        int s = L ^ (((L >> 9) & 1) << 5);
        int r = s >> 7, kel = (s & 127) >> 1;
        int gcol = colBase + h * 128 + r; gcol = gcol < M_COLS ? gcol : M_COLS - 1;
        return Bg + (size_t)gcol * KDIM + kel;
    };
    const unsigned short* gA00 = gsrcA(0, 0);
    const unsigned short* gA01 = gsrcA(0, 1);
    const unsigned short* gA10 = gsrcA(1, 0);
    const unsigned short* gA11 = gsrcA(1, 1);
    const unsigned short* gB00 = gsrcB(0, 0);
    const unsigned short* gB01 = gsrcB(0, 1);
    const unsigned short* gB10 = gsrcB(1, 0);
    const unsigned short* gB11 = gsrcB(1, 1);

    // ---- reader fragment LDS offsets (swizzled), fixed per thread ----
    int offA[8][2], offB[4][2];
    #pragma unroll
    for (int mi = 0; mi < 8; ++mi)
        #pragma unroll
        for (int kh = 0; kh < 2; ++kh) {
            int lin = (mi * 16 + l15) * 128 + kh * 64 + l4 * 16;
            int sw = lin ^ (((lin >> 9) & 1) << 5);
            offA[mi][kh] = (wm << 14) + sw;
        }
    #pragma unroll
    for (int ni = 0; ni < 4; ++ni)
        #pragma unroll
        for (int kh = 0; kh < 2; ++kh) {
            int cb = wn * 64 + ni * 16 + l15;
            int lin = (cb & 127) * 128 + kh * 64 + l4 * 16;
            int sw = lin ^ (((lin >> 9) & 1) << 5);
            offB[ni][kh] = 32768 + ((cb >> 7) << 14) + sw;
        }

    f32x4 acc[8][4] = {};

    // ---- prologue: K-tile 0 fully + B halves of K-tile 1; leave 2 halves in flight ----
    STAGE_A(0, 0); STAGE_A(1, 0); STAGE_B(0, 0); STAGE_B(1, 0);
    STAGE_B(0, 1); STAGE_B(1, 1);
    asm volatile("s_waitcnt vmcnt(4)" ::: "memory");
    __builtin_amdgcn_s_barrier();

    // ---- main loop: 4 phases per K-tile; stage A(c+1) at q0/q1, B(c+2) at q2/q3 ----
    for (int c = 0; c < NT; ++c) {
        const unsigned bufR = (unsigned)(c & 1) << 16;
        bf16x8 bf[4][2];
        #pragma unroll
        for (int ni = 0; ni < 4; ++ni) {
            bf[ni][0] = *(const bf16x8*)(smem + bufR + offB[ni][0]);
            bf[ni][1] = *(const bf16x8*)(smem + bufR + offB[ni][1]);
        }
        bf16x8 a_[2][2];
        // phase 0
        LDA2(0);
        if (c + 1 < NT) STAGE_A(0, c + 1);
        __builtin_amdgcn_s_barrier();
        __builtin_amdgcn_s_setprio(1);
        MFMA8(0);
        __builtin_amdgcn_s_setprio(0);
        __builtin_amdgcn_s_barrier();
        // phase 1
        LDA2(1);
        if (c + 1 < NT) STAGE_A(1, c + 1);
        __builtin_amdgcn_s_barrier();
        __builtin_amdgcn_s_setprio(1);
        MFMA8(1);
        __builtin_amdgcn_s_setprio(0);
        __builtin_amdgcn_s_barrier();
        // phase 2
        LDA2(2);
        if (c + 2 < NT) STAGE_B(0, c + 2);
        __builtin_amdgcn_s_barrier();
        __builtin_amdgcn_s_setprio(1);
        MFMA8(2);
        __builtin_amdgcn_s_setprio(0);
        __builtin_amdgcn_s_barrier();
        // phase 3 (+ counted vmcnt at the K-tile boundary)
        LDA2(3);
        if (c + 2 < NT) STAGE_B(1, c + 2);
        __builtin_amdgcn_s_barrier();
        __builtin_amdgcn_s_setprio(1);
        MFMA8(3);
        __builtin_amdgcn_s_setprio(0);
        if (c < NT - 2) { asm volatile("s_waitcnt vmcnt(4)" ::: "memory"); }
        else           { asm volatile("s_waitcnt vmcnt(0)" ::: "memory"); }
        __builtin_amdgcn_s_barrier();
    }

    // ---- epilogue: d^2 -> per-row top-9 over this 256-col tile (4 passes of 64 rows) ----
    float* EpiDs = (float*)smem;                 // [64][265] f32 (odd stride: conflict-free)
    float* EpiT9 = (float*)(smem + 68608);       // [8][64][12] f32
    int ncols = M_COLS - colBase; if (ncols > 256) ncols = 256;

    for (int p = 0; p < 4; ++p) {
        __syncthreads();
        if (wm == (p >> 1)) {
            float xv[4][4];
            #pragma unroll
            for (int ml = 0; ml < 4; ++ml)
                #pragma unroll
                for (int j = 0; j < 4; ++j) {
                    int gr = rowBase + p * 64 + ml * 16 + (l4 << 2) + j;
                    xv[ml][j] = x2[gr < N_ROWS ? gr : N_ROWS - 1];
                }
            #pragma unroll
            for (int ni = 0; ni < 4; ++ni) {
                int cc = wn * 64 + ni * 16 + l15;
                int gc = colBase + cc;
                float yv = y2[gc < M_COLS ? gc : M_COLS - 1];
                #pragma unroll
                for (int ml = 0; ml < 4; ++ml) {
                    int mi = ((p & 1) << 2) + ml;
                    #pragma unroll
                    for (int j = 0; j < 4; ++j) {
                        int rloc = ml * 16 + (l4 << 2) + j;
                        EpiDs[rloc * 265 + cc] = xv[ml][j] + yv - 2.0f * acc[mi][ni][j];
                    }
                }
            }
        }
        __syncthreads();
        float t9[9];
        #pragma unroll
        for (int s = 0; s < 9; ++s) t9[s] = 3.4e38f;
        {
            int cs = wid * 32, ce = cs + 32 < ncols ? cs + 32 : ncols;
            for (int cc = cs; cc < ce; ++cc)
                t9_insert(t9, EpiDs[lane * 265 + cc]);
        }
        // butterfly over the 8 column-block owners (per row) via LDS
        #pragma unroll
        for (int mm = 4; mm >= 1; mm >>= 1) {
            __syncthreads();
            #pragma unroll
            for (int s = 0; s < 9; ++s) EpiT9[(wid * 64 + lane) * 12 + s] = t9[s];
            __syncthreads();
            #pragma unroll
            for (int s = 0; s < 9; ++s)
                t9_insert(t9, EpiT9[((wid ^ mm) * 64 + lane) * 12 + s]);
        }
        if (wid == 0) {
            int gr = rowBase + p * 64 + lane;
            if (gr < N_ROWS) {
                float* dst = partials + (size_t)gr * PPR2 + ct * 9;
                #pragma unroll
                for (int s = 0; s < 9; ++s) dst[s] = t9[s];
            }
        }
        __syncthreads();
    }
}

// ---------- merge 79 sorted-9 lists per row -> final top-9 (one wave per row) ----------
__global__ void merge_topk_kernel(const float* __restrict__ partials,
                                  float* __restrict__ scores) {
    int lane = threadIdx.x & 63;
    int row = blockIdx.x * 4 + (threadIdx.x >> 6);   // 4 waves/block, 784 blocks
    const float* p = partials + (size_t)row * PPR2;
    float t9[9];
    #pragma unroll
    for (int s = 0; s < 9; ++s) t9[s] = 3.4e38f;
    for (int i = lane; i < PPR2; i += 64) {
        float v = p[i];
        if (v < t9[8]) t9_insert(t9, v);
    }
    #pragma unroll
    for (int off = 32; off > 0; off >>= 1) {
        float o[9];
        #pragma unroll
        for (int s = 0; s < 9; ++s) o[s] = __shfl_xor(t9[s], off);
        #pragma unroll
        for (int s = 0; s < 9; ++s)
            if (o[s] < t9[8]) t9_insert(t9, o[s]);
    }
    if (lane == 0) {
        #pragma unroll
        for (int s = 0; s < 9; ++s)
            scores[row * 9 + s] = sqrtf(fmaxf(t9[s], 0.f));
    }
}

// ---------- gaussian blur (fused with x8 nearest upsample), sigma=4, K=33 ----------
__global__ void blur_h_kernel(const float* __restrict__ scores, float* __restrict__ tH) {
    int idx = blockIdx.x * blockDim.x + threadIdx.x;
    if (idx >= 4 * 224 * 28) return;
    int pw = idx % 28, y = (idx / 28) % 224, b = idx / (28 * 224);
    float acc = 0.f, gsum = 0.f;
    #pragma unroll
    for (int k = 0; k < 33; ++k) {
        float xk = (float)(k - 16);
        float w = expf(-xk * xk * (1.0f / 32.0f));
        gsum += w;
        int yy = y - 16 + k;
        yy = yy < 0 ? -yy : yy;            // reflect
        yy = yy > 223 ? 446 - yy : yy;
        acc += w * scores[(size_t)(b * 784 + (yy >> 3) * 28 + pw) * 9];
    }
    tH[idx] = acc / gsum;
}

__global__ void blur_w_kernel(const float* __restrict__ tH, float* __restrict__ out) {
    int idx = blockIdx.x * blockDim.x + threadIdx.x;
    if (idx >= 4 * 224 * 224) return;
    int x = idx % 224, y = (idx / 224) % 224, b = idx / (224 * 224);
    float acc = 0.f, gsum = 0.f;
    #pragma unroll
    for (int k = 0; k < 33; ++k) {
        float xk = (float)(k - 16);
        float w = expf(-xk * xk * (1.0f / 32.0f));
        gsum += w;
        int xx = x - 16 + k;
        xx = xx < 0 ? -xx : xx;
        xx = xx > 223 ? 446 - xx : xx;
        acc += w * tH[(b * 224 + y) * 28 + (xx >> 3)];
    }
    out[idx] = acc / gsum;
}

// ---------- anomaly score ----------
__global__ void score_kernel(const float* __restrict__ scores, float* __restrict__ out) {
    __shared__ float vmax[256];
    __shared__ int   vidx[256];
    int tid = threadIdx.x;
    float best = -3.4e38f; int bi = 0x7fffffff;
    for (int r = tid; r < N_ROWS; r += 256) {
        float v = scores[r * 9];
        if (v > best) { best = v; bi = r; }
    }
    vmax[tid] = best; vidx[tid] = bi;
    __syncthreads();
    for (int s = 128; s > 0; s >>= 1) {
        if (tid < s) {
            if (vmax[tid + s] > vmax[tid] ||
                (vmax[tid + s] == vmax[tid] && vidx[tid + s] < vidx[tid])) {
                vmax[tid] = vmax[tid + s]; vidx[tid] = vidx[tid + s];
            }
        }
        __syncthreads();
    }
    if (tid == 0) {
        int idx = vidx[0];
        float es = 0.f, em = -3.4e38f;
        #pragma unroll
        for (int s = 0; s < 9; ++s) {
            float e = expf(scores[idx * 9 + s]);
            es += e; em = fmaxf(em, e);
        }
        out[4 * 224 * 224] = (1.0f - em / es) * vmax[0];
    }
}

// ---------- launch ----------
extern "C" void kernel_launch(void* const* d_in, const int* in_sizes, int n_in,
                              void* d_out, int out_size, void* d_ws, size_t ws_size,
                              hipStream_t stream) {
    const float* emb = (const float*)d_in[0];   // [3136,1536]
    const float* mb  = (const float*)d_in[1];   // [20000,1536]
    float* out = (float*)d_out;                 // 200704 amap + 1 score
    char* ws = (char*)d_ws;

    unsigned short* mbb      = (unsigned short*)(ws);             // 61,440,000 B
    unsigned short* embb     = (unsigned short*)(ws + 61440000);  //  9,633,792 B
    float*          x2       = (float*)(ws + 71073792);           //     12,544 B
    float*          y2       = (float*)(ws + 71086336);           //     80,000 B
    float*          partials = (float*)(ws + 71166464);           //  8,918,784 B
    float*          scores   = (float*)(ws + 80085248);           //    112,896 B
    float*          tH       = (float*)(ws + 80198144);           //    100,352 B

    cvt_norm_kernel<<<M_COLS / 4, 256, 0, stream>>>(mb, mbb, y2, M_COLS);
    cvt_norm_kernel<<<N_ROWS / 4, 256, 0, stream>>>(emb, embb, x2, N_ROWS);
    dist_topk_kernel<<<NWG, 512, 0, stream>>>(embb, mbb, x2, y2, partials);
    merge_topk_kernel<<<N_ROWS / 4, 256, 0, stream>>>(partials, scores);
    blur_h_kernel<<<(4 * 224 * 28 + 255) / 256, 256, 0, stream>>>(scores, tH);
    blur_w_kernel<<<(4 * 224 * 224 + 255) / 256, 256, 0, stream>>>(tH, out);
    score_kernel<<<1, 256, 0, stream>>>(scores, out);
}

// Round 4
// 433.642 us; speedup vs baseline: 1.3715x; 1.3715x over previous
//
#include <hip/hip_runtime.h>

// ---------- types ----------
typedef __attribute__((ext_vector_type(8))) short bf16x8;
typedef __attribute__((ext_vector_type(4))) float f32x4;

#define N_ROWS 3136
#define M_COLS 20000
#define KDIM   1536
#define BM     256
#define BN     256
#define BK     64
#define NT     24             // KDIM / BK
#define NCT2   79             // ceil(20000/256)
#define NRT2   13             // ceil(3136/256)
#define NWG    (NCT2 * NRT2)  // 1027
#define PPR2   (NCT2 * 9)     // 711

#define GLOAD_LDS16(g, l) __builtin_amdgcn_global_load_lds( \
    (const __attribute__((address_space(1))) unsigned int*)(g), \
    (__attribute__((address_space(3))) unsigned int*)(l), 16, 0, 0)

__device__ inline unsigned short f2bf(float f) {
    unsigned u = __float_as_uint(f);
    u += 0x7FFFu + ((u >> 16) & 1u);   // RNE
    return (unsigned short)(u >> 16);
}

// sorted ascending insert, drop old max; all indices static after unroll
__device__ inline void t9_insert(float (&t)[9], float v) {
    #pragma unroll
    for (int s = 8; s >= 1; --s)
        t[s] = (v <= t[s-1]) ? t[s-1] : fminf(t[s], v);
    t[0] = fminf(t[0], v);
}

// ---------- fused f32->bf16 conversion + row squared norms (wave per row) ----------
__global__ void cvt_norm_kernel(const float* __restrict__ src,
                                unsigned short* __restrict__ dst,
                                float* __restrict__ norms, int rows) {
    int lane = threadIdx.x & 63;
    int row = blockIdx.x * (blockDim.x >> 6) + (threadIdx.x >> 6);
    if (row >= rows) return;
    const float4* p = (const float4*)(src + (size_t)row * KDIM);
    ushort4* q = (ushort4*)(dst + (size_t)row * KDIM);
    float s = 0.f;
    #pragma unroll
    for (int i = 0; i < 6; ++i) {              // 384 float4 / 64 lanes
        float4 v = p[lane + i * 64];
        s += v.x*v.x + v.y*v.y + v.z*v.z + v.w*v.w;
        ushort4 o;
        o.x = f2bf(v.x); o.y = f2bf(v.y); o.z = f2bf(v.z); o.w = f2bf(v.w);
        q[lane + i * 64] = o;
    }
    #pragma unroll
    for (int off = 32; off > 0; off >>= 1) s += __shfl_down(s, off);
    if (lane == 0) norms[row] = s;
}

// ---------- fused distance GEMM + per-tile top-9 : 256x256 8-phase template ----------
// 8 waves (2M x 4N), BK=64, double-buffered 128 KiB LDS,
// swizzle byte ^= ((row&7)<<4) within each 128-B row (G4 form, 3-bit spread),
// counted vmcnt(4) at K-tile boundaries, setprio around MFMA clusters.
// LDS per buffer (64 KiB): A0[128][64] | A1 | B0 | B1  (16 KiB halves, rows of 128 B).

#define STAGE_A(h, s_) do { \
    unsigned dstb = ((unsigned)((s_) & 1) << 16) + ((h) << 14) + ((unsigned)tid << 4); \
    GLOAD_LDS16(gA##h##0 + (size_t)(s_) * BK, smem + dstb); \
    GLOAD_LDS16(gA##h##1 + (size_t)(s_) * BK, smem + dstb + 8192); \
} while (0)
#define STAGE_B(h, s_) do { \
    unsigned dstb = ((unsigned)((s_) & 1) << 16) + 32768u + ((h) << 14) + ((unsigned)tid << 4); \
    GLOAD_LDS16(gB##h##0 + (size_t)(s_) * BK, smem + dstb); \
    GLOAD_LDS16(gB##h##1 + (size_t)(s_) * BK, smem + dstb + 8192); \
} while (0)

#define LDA2(q) \
    a_[0][0] = *(const bf16x8*)(smem + bufR + aBase0 + (2*(q)  )*2048); \
    a_[0][1] = *(const bf16x8*)(smem + bufR + aBase1 + (2*(q)  )*2048); \
    a_[1][0] = *(const bf16x8*)(smem + bufR + aBase0 + (2*(q)+1)*2048); \
    a_[1][1] = *(const bf16x8*)(smem + bufR + aBase1 + (2*(q)+1)*2048);

#define MFMA8(q) \
    _Pragma("unroll") \
    for (int m = 0; m < 2; ++m) { \
        _Pragma("unroll") \
        for (int ni = 0; ni < 4; ++ni) { \
            acc[2*(q)+m][ni] = __builtin_amdgcn_mfma_f32_16x16x32_bf16(a_[m][0], bf[ni][0], acc[2*(q)+m][ni], 0, 0, 0); \
            acc[2*(q)+m][ni] = __builtin_amdgcn_mfma_f32_16x16x32_bf16(a_[m][1], bf[ni][1], acc[2*(q)+m][ni], 0, 0, 0); \
        } \
    }

__global__ __launch_bounds__(512, 2) void dist_topk_kernel(
    const unsigned short* __restrict__ Ag,   // [3136][1536] bf16
    const unsigned short* __restrict__ Bg,   // [20000][1536] bf16
    const float* __restrict__ x2, const float* __restrict__ y2,
    float* __restrict__ partials)
{
    __shared__ __align__(16) unsigned char smem[131072];

    const int tid = threadIdx.x;
    const int wid = tid >> 6, lane = tid & 63;
    const int l15 = lane & 15, l4 = lane >> 4;
    const int wm = wid >> 2, wn = wid & 3;

    // bijective XCD swizzle (m204; 1027 % 8 != 0)
    int orig = blockIdx.x;
    int xcd = orig & 7, li = orig >> 3;
    const int qq = NWG / 8, rr = NWG % 8;   // 128, 3
    int wg = (xcd < rr ? xcd * (qq + 1) : rr * (qq + 1) + (xcd - rr) * qq) + li;
    const int rt = wg / NCT2, ct = wg % NCT2;
    const int rowBase = rt * BM, colBase = ct * BN;

    // ---- staging source pointers: inverse-swizzled global source, linear LDS dest ----
    // swizzle: s = L ^ (((L>>7)&7)<<4)  (involution; bits 4-6 from row bits 0-2)
    auto gsrcA = [&](int h, int j) {
        int L = ((j << 9) + tid) << 4;                  // linear dest byte in 16 KiB half
        int s = L ^ (((L >> 7) & 7) << 4);
        int r = s >> 7, kel = (s & 127) >> 1;
        int grow = rowBase + h * 128 + r; grow = grow < N_ROWS ? grow : N_ROWS - 1;
        return Ag + (size_t)grow * KDIM + kel;
    };
    auto gsrcB = [&](int h, int j) {
        int L = ((j << 9) + tid) << 4;
        int s = L ^ (((L >> 7) & 7) << 4);
        int r = s >> 7, kel = (s & 127) >> 1;
        int gcol = colBase + h * 128 + r; gcol = gcol < M_COLS ? gcol : M_COLS - 1;
        return Bg + (size_t)gcol * KDIM + kel;
    };
    const unsigned short* gA00 = gsrcA(0, 0);
    const unsigned short* gA01 = gsrcA(0, 1);
    const unsigned short* gA10 = gsrcA(1, 0);
    const unsigned short* gA11 = gsrcA(1, 1);
    const unsigned short* gB00 = gsrcB(0, 0);
    const unsigned short* gB01 = gsrcB(0, 1);
    const unsigned short* gB10 = gsrcB(1, 0);
    const unsigned short* gB11 = gsrcB(1, 1);

    // ---- reader fragment LDS base offsets (swizzled). row&7 == l15&7 for all
    // fragments (mi*16, ni*16, wn*64 are ≡0 mod 8), so swz is mi/ni-invariant and
    // offsets are base + {mi,ni}*2048 (folds into ds_read offset immediates). ----
    const int swz = (l15 & 7) << 4;
    const int C0 = l4 * 16, C1 = 64 + l4 * 16;
    const int aBase0 = (wm << 14) + l15 * 128 + (C0 ^ swz);
    const int aBase1 = (wm << 14) + l15 * 128 + (C1 ^ swz);
    const int bBase0 = 32768 + ((wn >> 1) << 14) + ((wn & 1) * 64 + l15) * 128 + (C0 ^ swz);
    const int bBase1 = 32768 + ((wn >> 1) << 14) + ((wn & 1) * 64 + l15) * 128 + (C1 ^ swz);

    f32x4 acc[8][4] = {};

    // ---- prologue: K-tile 0 fully + B halves of K-tile 1; leave 4 loads in flight ----
    STAGE_A(0, 0); STAGE_A(1, 0); STAGE_B(0, 0); STAGE_B(1, 0);
    STAGE_B(0, 1); STAGE_B(1, 1);
    asm volatile("s_waitcnt vmcnt(4)" ::: "memory");
    __builtin_amdgcn_s_barrier();

    // ---- main loop: 4 phases per K-tile; stage A(c+1) at q0/q1, B(c+2) at q2/q3 ----
    for (int c = 0; c < NT; ++c) {
        const unsigned bufR = (unsigned)(c & 1) << 16;
        bf16x8 bf[4][2];
        #pragma unroll
        for (int ni = 0; ni < 4; ++ni) {
            bf[ni][0] = *(const bf16x8*)(smem + bufR + bBase0 + ni * 2048);
            bf[ni][1] = *(const bf16x8*)(smem + bufR + bBase1 + ni * 2048);
        }
        bf16x8 a_[2][2];
        // phase 0
        LDA2(0);
        if (c + 1 < NT) STAGE_A(0, c + 1);
        __builtin_amdgcn_s_barrier();
        __builtin_amdgcn_s_setprio(1);
        MFMA8(0);
        __builtin_amdgcn_s_setprio(0);
        __builtin_amdgcn_s_barrier();
        // phase 1
        LDA2(1);
        if (c + 1 < NT) STAGE_A(1, c + 1);
        __builtin_amdgcn_s_barrier();
        __builtin_amdgcn_s_setprio(1);
        MFMA8(1);
        __builtin_amdgcn_s_setprio(0);
        __builtin_amdgcn_s_barrier();
        // phase 2
        LDA2(2);
        if (c + 2 < NT) STAGE_B(0, c + 2);
        __builtin_amdgcn_s_barrier();
        __builtin_amdgcn_s_setprio(1);
        MFMA8(2);
        __builtin_amdgcn_s_setprio(0);
        __builtin_amdgcn_s_barrier();
        // phase 3 (+ counted vmcnt at the K-tile boundary)
        LDA2(3);
        if (c + 2 < NT) STAGE_B(1, c + 2);
        __builtin_amdgcn_s_barrier();
        __builtin_amdgcn_s_setprio(1);
        MFMA8(3);
        __builtin_amdgcn_s_setprio(0);
        if (c < NT - 2) { asm volatile("s_waitcnt vmcnt(4)" ::: "memory"); }
        else           { asm volatile("s_waitcnt vmcnt(0)" ::: "memory"); }
        __builtin_amdgcn_s_barrier();
    }

    // ---- epilogue: d^2 -> per-row top-9 over this 256-col tile (4 passes of 64 rows)
    // p-loop UNROLLED so every acc index is compile-time (rule #20: no scratch). ----
    float* EpiDs = (float*)smem;                 // [64][265] f32 (odd stride: conflict-free)
    float* EpiT9 = (float*)(smem + 68608);       // [8][64][12] f32
    int ncols = M_COLS - colBase; if (ncols > 256) ncols = 256;

    #pragma unroll
    for (int p = 0; p < 4; ++p) {
        __syncthreads();
        if (wm == (p >> 1)) {
            float xv[4][4];
            #pragma unroll
            for (int ml = 0; ml < 4; ++ml)
                #pragma unroll
                for (int j = 0; j < 4; ++j) {
                    int gr = rowBase + p * 64 + ml * 16 + (l4 << 2) + j;
                    xv[ml][j] = x2[gr < N_ROWS ? gr : N_ROWS - 1];
                }
            #pragma unroll
            for (int ni = 0; ni < 4; ++ni) {
                int cc = wn * 64 + ni * 16 + l15;
                int gc = colBase + cc;
                float yv = y2[gc < M_COLS ? gc : M_COLS - 1];
                #pragma unroll
                for (int ml = 0; ml < 4; ++ml) {
                    #pragma unroll
                    for (int j = 0; j < 4; ++j) {
                        int rloc = ml * 16 + (l4 << 2) + j;
                        EpiDs[rloc * 265 + cc] = xv[ml][j] + yv - 2.0f * acc[((p & 1) << 2) + ml][ni][j];
                    }
                }
            }
        }
        __syncthreads();
        float t9[9];
        #pragma unroll
        for (int s = 0; s < 9; ++s) t9[s] = 3.4e38f;
        {
            int cs = wid * 32, ce = cs + 32 < ncols ? cs + 32 : ncols;
            for (int cc = cs; cc < ce; ++cc)
                t9_insert(t9, EpiDs[lane * 265 + cc]);
        }
        // butterfly over the 8 column-block owners (per row) via LDS
        #pragma unroll
        for (int mm = 4; mm >= 1; mm >>= 1) {
            __syncthreads();
            #pragma unroll
            for (int s = 0; s < 9; ++s) EpiT9[(wid * 64 + lane) * 12 + s] = t9[s];
            __syncthreads();
            #pragma unroll
            for (int s = 0; s < 9; ++s)
                t9_insert(t9, EpiT9[((wid ^ mm) * 64 + lane) * 12 + s]);
        }
        if (wid == 0) {
            int gr = rowBase + p * 64 + lane;
            if (gr < N_ROWS) {
                float* dst = partials + (size_t)gr * PPR2 + ct * 9;
                #pragma unroll
                for (int s = 0; s < 9; ++s) dst[s] = t9[s];
            }
        }
        __syncthreads();
    }
}

// ---------- merge 79 sorted-9 lists per row -> final top-9 (one wave per row) ----------
__global__ void merge_topk_kernel(const float* __restrict__ partials,
                                  float* __restrict__ scores) {
    int lane = threadIdx.x & 63;
    int row = blockIdx.x * 4 + (threadIdx.x >> 6);   // 4 waves/block, 784 blocks
    const float* p = partials + (size_t)row * PPR2;
    float t9[9];
    #pragma unroll
    for (int s = 0; s < 9; ++s) t9[s] = 3.4e38f;
    for (int i = lane; i < PPR2; i += 64) {
        float v = p[i];
        if (v < t9[8]) t9_insert(t9, v);
    }
    #pragma unroll
    for (int off = 32; off > 0; off >>= 1) {
        float o[9];
        #pragma unroll
        for (int s = 0; s < 9; ++s) o[s] = __shfl_xor(t9[s], off);
        #pragma unroll
        for (int s = 0; s < 9; ++s)
            if (o[s] < t9[8]) t9_insert(t9, o[s]);
    }
    if (lane == 0) {
        #pragma unroll
        for (int s = 0; s < 9; ++s)
            scores[row * 9 + s] = sqrtf(fmaxf(t9[s], 0.f));
    }
}

// ---------- gaussian blur (fused with x8 nearest upsample), sigma=4, K=33 ----------
__global__ void blur_h_kernel(const float* __restrict__ scores, float* __restrict__ tH) {
    int idx = blockIdx.x * blockDim.x + threadIdx.x;
    if (idx >= 4 * 224 * 28) return;
    int pw = idx % 28, y = (idx / 28) % 224, b = idx / (28 * 224);
    float acc = 0.f, gsum = 0.f;
    #pragma unroll
    for (int k = 0; k < 33; ++k) {
        float xk = (float)(k - 16);
        float w = expf(-xk * xk * (1.0f / 32.0f));
        gsum += w;
        int yy = y - 16 + k;
        yy = yy < 0 ? -yy : yy;            // reflect
        yy = yy > 223 ? 446 - yy : yy;
        acc += w * scores[(size_t)(b * 784 + (yy >> 3) * 28 + pw) * 9];
    }
    tH[idx] = acc / gsum;
}

__global__ void blur_w_kernel(const float* __restrict__ tH, float* __restrict__ out) {
    int idx = blockIdx.x * blockDim.x + threadIdx.x;
    if (idx >= 4 * 224 * 224) return;
    int x = idx % 224, y = (idx / 224) % 224, b = idx / (224 * 224);
    float acc = 0.f, gsum = 0.f;
    #pragma unroll
    for (int k = 0; k < 33; ++k) {
        float xk = (float)(k - 16);
        float w = expf(-xk * xk * (1.0f / 32.0f));
        gsum += w;
        int xx = x - 16 + k;
        xx = xx < 0 ? -xx : xx;
        xx = xx > 223 ? 446 - xx : xx;
        acc += w * tH[(b * 224 + y) * 28 + (xx >> 3)];
    }
    out[idx] = acc / gsum;
}

// ---------- anomaly score ----------
__global__ void score_kernel(const float* __restrict__ scores, float* __restrict__ out) {
    __shared__ float vmax[256];
    __shared__ int   vidx[256];
    int tid = threadIdx.x;
    float best = -3.4e38f; int bi = 0x7fffffff;
    for (int r = tid; r < N_ROWS; r += 256) {
        float v = scores[r * 9];
        if (v > best) { best = v; bi = r; }
    }
    vmax[tid] = best; vidx[tid] = bi;
    __syncthreads();
    for (int s = 128; s > 0; s >>= 1) {
        if (tid < s) {
            if (vmax[tid + s] > vmax[tid] ||
                (vmax[tid + s] == vmax[tid] && vidx[tid + s] < vidx[tid])) {
                vmax[tid] = vmax[tid + s]; vidx[tid] = vidx[tid + s];
            }
        }
        __syncthreads();
    }
    if (tid == 0) {
        int idx = vidx[0];
        float es = 0.f, em = -3.4e38f;
        #pragma unroll
        for (int s = 0; s < 9; ++s) {
            float e = expf(scores[idx * 9 + s]);
            es += e; em = fmaxf(em, e);
        }
        out[4 * 224 * 224] = (1.0f - em / es) * vmax[0];
    }
}

// ---------- launch ----------
extern "C" void kernel_launch(void* const* d_in, const int* in_sizes, int n_in,
                              void* d_out, int out_size, void* d_ws, size_t ws_size,
                              hipStream_t stream) {
    const float* emb = (const float*)d_in[0];   // [3136,1536]
    const float* mb  = (const float*)d_in[1];   // [20000,1536]
    float* out = (float*)d_out;                 // 200704 amap + 1 score
    char* ws = (char*)d_ws;

    unsigned short* mbb      = (unsigned short*)(ws);             // 61,440,000 B
    unsigned short* embb     = (unsigned short*)(ws + 61440000);  //  9,633,792 B
    float*          x2       = (float*)(ws + 71073792);           //     12,544 B
    float*          y2       = (float*)(ws + 71086336);           //     80,000 B
    float*          partials = (float*)(ws + 71166464);           //  8,918,784 B
    float*          scores   = (float*)(ws + 80085248);           //    112,896 B
    float*          tH       = (float*)(ws + 80198144);           //    100,352 B

    cvt_norm_kernel<<<M_COLS / 4, 256, 0, stream>>>(mb, mbb, y2, M_COLS);
    cvt_norm_kernel<<<N_ROWS / 4, 256, 0, stream>>>(emb, embb, x2, N_ROWS);
    dist_topk_kernel<<<NWG, 512, 0, stream>>>(embb, mbb, x2, y2, partials);
    merge_topk_kernel<<<N_ROWS / 4, 256, 0, stream>>>(partials, scores);
    blur_h_kernel<<<(4 * 224 * 28 + 255) / 256, 256, 0, stream>>>(scores, tH);
    blur_w_kernel<<<(4 * 224 * 224 + 255) / 256, 256, 0, stream>>>(tH, out);
    score_kernel<<<1, 256, 0, stream>>>(scores, out);
}